// Round 9
// baseline (176.459 us; speedup 1.0000x reference)
//
#include <hip/hip_runtime.h>

#define N_ROWS 200000
#define D_IN   256
#define D_LAT  64
#define K_CL   100
#define NT     7            // 7 cluster tiles of 16 -> 112 (cols >=100 masked)
#define TPB    256

#define GRPS    3125        // row groups of 64 (4 waves x 16 rows)
#define NBLK    1024        // blocks per dispatch (4 blocks/CU, fully resident)
#define SC_HALF 3125        // 32KB stream chunks per dispatch (6250 total)
#define NSLOT   64

typedef __attribute__((ext_vector_type(8))) short bf16x8;
typedef __attribute__((ext_vector_type(4))) float f32x4;

__device__ __forceinline__ float rcpf(float x) { return __builtin_amdgcn_rcpf(x); }

__device__ __forceinline__ short f2bf(float f) {
    union { float f; unsigned u; } v; v.f = f;
    unsigned r = (v.u + 0x7fffu + ((v.u >> 16) & 1u)) >> 16;
    return (short)r;
}

__device__ __forceinline__ void cvt8r(float4 a, float4 b, bf16x8& o, float& sq) {
    sq = fmaf(a.x, a.x, sq); sq = fmaf(a.y, a.y, sq);
    sq = fmaf(a.z, a.z, sq); sq = fmaf(a.w, a.w, sq);
    sq = fmaf(b.x, b.x, sq); sq = fmaf(b.y, b.y, sq);
    sq = fmaf(b.z, b.z, sq); sq = fmaf(b.w, b.w, sq);
    o[0] = f2bf(a.x); o[1] = f2bf(a.y); o[2] = f2bf(a.z); o[3] = f2bf(a.w);
    o[4] = f2bf(b.x); o[5] = f2bf(b.y); o[6] = f2bf(b.z); o[7] = f2bf(b.w);
}

__device__ __forceinline__ void cvt8(const float* __restrict__ p, bf16x8& o, float& sq) {
    float4 a = *(const float4*)p;
    float4 b = *(const float4*)(p + 4);
    cvt8r(a, b, o, sq);
}

template<bool NTL>
__device__ __forceinline__ f32x4 ldf(const f32x4* __restrict__ p) {
    if constexpr (NTL) return __builtin_nontemporal_load(p);
    else return *p;
}

// ---- lane ids ----
#define LANE_IDS()                                                             \
    const int tid = threadIdx.x;                                               \
    const int l   = tid & 63;                                                  \
    const int w   = tid >> 6;                                                  \
    const int c16 = l & 15;                                                    \
    const int g   = l >> 4;

// ---- B fragments + ||c||^2 in-register ----
#define PROLOGUE_B()                                                           \
    bf16x8 bfrag[NT][2];                                                       \
    float  cn2v[NT];                                                           \
    _Pragma("unroll")                                                          \
    for (int t = 0; t < NT; ++t) {                                             \
        int col = t * 16 + c16;                                                \
        bool valid = col < K_CL;                                               \
        float sq = 0.f;                                                        \
        _Pragma("unroll")                                                      \
        for (int kt = 0; kt < 2; ++kt) {                                       \
            bf16x8 bf;                                                         \
            if (valid) {                                                       \
                cvt8(cen + col * D_LAT + kt * 32 + g * 8, bf, sq);             \
            } else {                                                           \
                _Pragma("unroll")                                              \
                for (int i = 0; i < 8; ++i) bf[i] = 0;                         \
            }                                                                  \
            bfrag[t][kt] = bf;                                                 \
        }                                                                      \
        sq += __shfl_xor(sq, 16);                                              \
        sq += __shfl_xor(sq, 32);                                              \
        cn2v[t] = sq;                                                          \
    }                                                                          \
    const bool v6 = (c16 < 4); /* tile 6: cols 96..111, valid < 100 */

// ---- issue one group's enc loads into a named float4[4] ----
#define LOADS4(grp, A)                                                         \
    {                                                                          \
        const int rowbase_ = (grp) * 64 + w * 16;                              \
        const float* arow_ = enc + (size_t)(rowbase_ + c16) * D_LAT + g * 8;   \
        A[0] = *(const float4*)(arow_);                                        \
        A[1] = *(const float4*)(arow_ + 4);                                    \
        A[2] = *(const float4*)(arow_ + 32);                                   \
        A[3] = *(const float4*)(arow_ + 36);                                   \
    }

// ---- convert, MFMA dot, q + row-sums -> qv[NT][4], rs[4] (reads A[0..3]) ----
#define GROUP_COMPUTE_FROM(A)                                                  \
    float en2p = 0.f;                                                          \
    bf16x8 afrag0, afrag1;                                                     \
    cvt8r(A[0], A[1], afrag0, en2p);                                           \
    cvt8r(A[2], A[3], afrag1, en2p);                                           \
    en2p += __shfl_xor(en2p, 16);                                              \
    en2p += __shfl_xor(en2p, 32);                                              \
    f32x4 acc[NT];                                                             \
    _Pragma("unroll")                                                          \
    for (int t = 0; t < NT; ++t) {                                             \
        acc[t][0] = 0.f; acc[t][1] = 0.f; acc[t][2] = 0.f; acc[t][3] = 0.f;    \
    }                                                                          \
    _Pragma("unroll")                                                          \
    for (int t = 0; t < NT; ++t)                                               \
        acc[t] = __builtin_amdgcn_mfma_f32_16x16x32_bf16(afrag0, bfrag[t][0], acc[t], 0, 0, 0); \
    _Pragma("unroll")                                                          \
    for (int t = 0; t < NT; ++t)                                               \
        acc[t] = __builtin_amdgcn_mfma_f32_16x16x32_bf16(afrag1, bfrag[t][1], acc[t], 0, 0, 0); \
    float en2r[4];                                                             \
    _Pragma("unroll")                                                          \
    for (int r = 0; r < 4; ++r) en2r[r] = __shfl(en2p, g * 4 + r);             \
    float qv[NT][4];                                                           \
    float rs[4] = {0.f, 0.f, 0.f, 0.f};                                        \
    _Pragma("unroll")                                                          \
    for (int t = 0; t < NT; ++t) {                                             \
        _Pragma("unroll")                                                      \
        for (int r = 0; r < 4; ++r) {                                          \
            float d2 = en2r[r] + cn2v[t] - 2.f * acc[t][r];                    \
            float q = rcpf(1.f + fmaxf(d2, 0.f));                              \
            if (t == 6 && !v6) q = 0.f;                                        \
            qv[t][r] = q; rs[r] += q;                                          \
        }                                                                      \
    }                                                                          \
    _Pragma("unroll")                                                          \
    for (int r = 0; r < 4; ++r) {                                              \
        rs[r] += __shfl_xor(rs[r], 1); rs[r] += __shfl_xor(rs[r], 2);          \
        rs[r] += __shfl_xor(rs[r], 4); rs[r] += __shfl_xor(rs[r], 8);          \
        rs[r] = rcpf(rs[r]);                                                   \
    }

// ---- grid-stride ping-pong over groups: ~3 groups/block, 2-deep prefetch ----
#define GROUP_LOOP(PROCESS)                                                    \
    {                                                                          \
        int grp_ = (int)blockIdx.x;                                            \
        float4 A0_[4], A1_[4];                                                 \
        LOADS4(grp_, A0_);                                                     \
        while (true) {                                                         \
            int n1_ = grp_ + NBLK;                                             \
            if (n1_ < GRPS) LOADS4(n1_, A1_);                                  \
            { PROCESS(A0_); }                                                  \
            if (n1_ >= GRPS) break;                                            \
            int n2_ = n1_ + NBLK;                                              \
            if (n2_ < GRPS) LOADS4(n2_, A0_);                                  \
            { PROCESS(A1_); }                                                  \
            if (n2_ >= GRPS) break;                                            \
            grp_ = n2_;                                                        \
        }                                                                      \
    }

#define PROCESS_P1(A)                                                          \
    {                                                                          \
        GROUP_COMPUTE_FROM(A);                                                 \
        _Pragma("unroll")                                                      \
        for (int t = 0; t < NT; ++t) {                                         \
            float aa = 0.f;                                                    \
            _Pragma("unroll")                                                  \
            for (int r = 0; r < 4; ++r) aa = fmaf(qv[t][r], rs[r], aa);        \
            facc[t] += aa;                                                     \
        }                                                                      \
    }

#define PROCESS_P2(A)                                                          \
    {                                                                          \
        GROUP_COMPUTE_FROM(A);                                                 \
        float tac[4] = {0.f, 0.f, 0.f, 0.f};                                   \
        float Ap[4]  = {0.f, 0.f, 0.f, 0.f};                                   \
        float Bp[4]  = {0.f, 0.f, 0.f, 0.f};                                   \
        _Pragma("unroll")                                                      \
        for (int t = 0; t < NT; ++t) {                                         \
            _Pragma("unroll")                                                  \
            for (int r = 0; r < 4; ++r) {                                      \
                if (t == 6 && !v6) continue;  /* masked col: q==0 */           \
                float q = qv[t][r] * rs[r];                                    \
                float pu = q * q * rfv[t];                                     \
                tac[r] += pu;                                                  \
                Ap[r] = fmaf(pu, __logf(q), Ap[r]);                            \
                Bp[r] = fmaf(pu, lfv[t], Bp[r]);                               \
            }                                                                  \
        }                                                                      \
        _Pragma("unroll")                                                      \
        for (int r = 0; r < 4; ++r) {                                          \
            tac[r] += __shfl_xor(tac[r], 1); tac[r] += __shfl_xor(tac[r], 2);  \
            tac[r] += __shfl_xor(tac[r], 4); tac[r] += __shfl_xor(tac[r], 8);  \
            Ap[r]  += __shfl_xor(Ap[r], 1);  Ap[r]  += __shfl_xor(Ap[r], 2);   \
            Ap[r]  += __shfl_xor(Ap[r], 4);  Ap[r]  += __shfl_xor(Ap[r], 8);   \
            Bp[r]  += __shfl_xor(Bp[r], 1);  Bp[r]  += __shfl_xor(Bp[r], 2);   \
            Bp[r]  += __shfl_xor(Bp[r], 4);  Bp[r]  += __shfl_xor(Bp[r], 8);   \
        }                                                                      \
        if (c16 == 0) {                                                        \
            _Pragma("unroll")                                                  \
            for (int r = 0; r < 4; ++r)                                        \
                kl_local += (Ap[r] - Bp[r]) * rcpf(tac[r]) - __logf(tac[r]);   \
        }                                                                      \
    }

// ---- decoder-loss stream phase: ~3 chunks/block, 16 loads in flight ----
template<bool NTL>
__device__ __forceinline__ void stream_phase(const f32x4* __restrict__ X,
                                             const f32x4* __restrict__ Dec,
                                             double* __restrict__ slots,
                                             int bid, int cbase) {
    float local = 0.f;
#pragma unroll 1
    for (int c = bid; c < SC_HALF; c += NBLK) {
        const int idx = (cbase + c) * 2048 + (int)threadIdx.x;
        f32x4 a[8], b[8];
#pragma unroll
        for (int u = 0; u < 8; ++u) a[u] = ldf<NTL>(X + idx + u * 256);
#pragma unroll
        for (int u = 0; u < 8; ++u) b[u] = ldf<NTL>(Dec + idx + u * 256);
        __builtin_amdgcn_sched_barrier(0);   // pin: all 16 loads issued before use
#pragma unroll
        for (int u = 0; u < 8; ++u) {
            f32x4 d = a[u] - b[u];
            local = fmaf(d.x, d.x, local); local = fmaf(d.y, d.y, local);
            local = fmaf(d.z, d.z, local); local = fmaf(d.w, d.w, local);
        }
    }
    __shared__ float sred[TPB];
    sred[threadIdx.x] = local;
    __syncthreads();
    for (int off = TPB / 2; off > 0; off >>= 1) {
        if (threadIdx.x < off) sred[threadIdx.x] += sred[threadIdx.x + off];
        __syncthreads();
    }
    if (threadIdx.x == 0) atomicAdd(&slots[bid & (NSLOT - 1)], (double)sred[0]);
    __syncthreads();
}

// ---- dispatch 1: every block = stream chunks + pass1 groups (order by parity) ----
__global__ void __launch_bounds__(TPB, 4) k_d1(const f32x4* __restrict__ X,
                                               const f32x4* __restrict__ Xdec,
                                               const float* __restrict__ enc,
                                               const float* __restrict__ cen,
                                               double* __restrict__ dec_slots,
                                               float* __restrict__ fg) {
    LANE_IDS();
    const int bid = blockIdx.x;
    const bool streamFirst = (bid & 1);
    if (streamFirst) stream_phase<false>(X, Xdec, dec_slots, bid, 0);
    {
        PROLOGUE_B();
        float facc[NT];
#pragma unroll
        for (int t = 0; t < NT; ++t) facc[t] = 0.f;
        GROUP_LOOP(PROCESS_P1);
        __shared__ float f_s[K_CL];
        for (int i = tid; i < K_CL; i += TPB) f_s[i] = 0.f;
        __syncthreads();
#pragma unroll
        for (int t = 0; t < NT; ++t) {
            float a = facc[t];
            a += __shfl_xor(a, 16);
            a += __shfl_xor(a, 32);
            int col = t * 16 + c16;
            if (g == 0 && col < K_CL) atomicAdd(&f_s[col], a);
        }
        __syncthreads();
        for (int i = tid; i < K_CL; i += TPB) atomicAdd(&fg[i], f_s[i]);
        __syncthreads();
    }
    if (!streamFirst) stream_phase<false>(X, Xdec, dec_slots, bid, 0);
}

// ---- dispatch 2: every block = stream chunks (nt) + pass2 groups ----
__global__ void __launch_bounds__(TPB, 4) k_d2(const f32x4* __restrict__ X,
                                               const f32x4* __restrict__ Xdec,
                                               const float* __restrict__ enc,
                                               const float* __restrict__ cen,
                                               const float* __restrict__ fg,
                                               double* __restrict__ dec_slots,
                                               double* __restrict__ kl_slots) {
    LANE_IDS();
    const int bid = blockIdx.x;
    const bool streamFirst = (bid & 1);
    if (streamFirst) stream_phase<true>(X, Xdec, dec_slots, bid, SC_HALF);
    {
        PROLOGUE_B();
        float lfv[NT], rfv[NT];
#pragma unroll
        for (int t = 0; t < NT; ++t) {
            int col = t * 16 + c16;
            if (col < K_CL) {
                float fv = fg[col];
                lfv[t] = __logf(fv);
                rfv[t] = rcpf(fv);
            } else { lfv[t] = 0.f; rfv[t] = 0.f; }
        }
        float kl_local = 0.f;
        GROUP_LOOP(PROCESS_P2);
        __shared__ float red[TPB];
        red[tid] = kl_local;
        __syncthreads();
        for (int off = TPB / 2; off > 0; off >>= 1) {
            if (tid < off) red[tid] += red[tid + off];
            __syncthreads();
        }
        if (tid == 0) atomicAdd(&kl_slots[bid & (NSLOT - 1)], (double)red[0]);
        __syncthreads();
    }
    if (!streamFirst) stream_phase<true>(X, Xdec, dec_slots, bid, SC_HALF);
}

__global__ void k_final(const double* __restrict__ dec_s,
                        const double* __restrict__ kl_s,
                        float* __restrict__ out) {
    int l = threadIdx.x;     // 64 threads = one wave
    double d = dec_s[l];
    double k = kl_s[l];
#pragma unroll
    for (int off = 32; off > 0; off >>= 1) {
        d += __shfl_xor(d, off);
        k += __shfl_xor(k, off);
    }
    if (l == 0)
        out[0] = (float)(d / ((double)N_ROWS * (double)D_IN) + 1000.0 * (k / (double)N_ROWS));
}

extern "C" void kernel_launch(void* const* d_in, const int* in_sizes, int n_in,
                              void* d_out, int out_size, void* d_ws, size_t ws_size,
                              hipStream_t stream) {
    (void)in_sizes; (void)n_in; (void)out_size; (void)ws_size;
    const float* X   = (const float*)d_in[0];
    const float* enc = (const float*)d_in[1];
    const float* dec = (const float*)d_in[2];
    const float* cen = (const float*)d_in[3];
    float* out = (float*)d_out;

    double* dec_slots = (double*)d_ws;                       // 64 doubles
    double* kl_slots  = (double*)((char*)d_ws + 512);        // 64 doubles
    float*  fg        = (float*)((char*)d_ws + 1024);        // 128 floats

    hipMemsetAsync(d_ws, 0, 1536, stream);
    k_d1<<<NBLK, TPB, 0, stream>>>(
        (const f32x4*)X, (const f32x4*)dec, enc, cen, dec_slots, fg);
    k_d2<<<NBLK, TPB, 0, stream>>>(
        (const f32x4*)X, (const f32x4*)dec, enc, cen, fg, dec_slots, kl_slots);
    k_final<<<1, 64, 0, stream>>>(dec_slots, kl_slots, out);
}

// Round 10
// 145.600 us; speedup vs baseline: 1.2119x; 1.2119x over previous
//
#include <hip/hip_runtime.h>

#define N_ROWS 200000
#define D_IN   256
#define D_LAT  64
#define K_CL   100
#define NT     7            // 7 cluster tiles of 16 -> 112 (cols >=100 masked)
#define TPB    256

#define GRPS   3125         // row groups of 64 (4 waves x 16 rows)
#define NMF    625          // MFMA blocks per dispatch
#define GPB    5            // groups per MFMA block (3125/625)

// stream geometry: 12.8e6 float4s per array = 6250 chunks of 2048 (32 KB/array)
#define SC_HALF   3125      // chunks (= stream blocks) per dispatch
#define NSLOT     64

typedef __attribute__((ext_vector_type(8))) short bf16x8;
typedef __attribute__((ext_vector_type(4))) float f32x4;

__device__ __forceinline__ float rcpf(float x) { return __builtin_amdgcn_rcpf(x); }

__device__ __forceinline__ short f2bf(float f) {
    union { float f; unsigned u; } v; v.f = f;
    unsigned r = (v.u + 0x7fffu + ((v.u >> 16) & 1u)) >> 16;
    return (short)r;
}

__device__ __forceinline__ void cvt8r(float4 a, float4 b, bf16x8& o, float& sq) {
    sq = fmaf(a.x, a.x, sq); sq = fmaf(a.y, a.y, sq);
    sq = fmaf(a.z, a.z, sq); sq = fmaf(a.w, a.w, sq);
    sq = fmaf(b.x, b.x, sq); sq = fmaf(b.y, b.y, sq);
    sq = fmaf(b.z, b.z, sq); sq = fmaf(b.w, b.w, sq);
    o[0] = f2bf(a.x); o[1] = f2bf(a.y); o[2] = f2bf(a.z); o[3] = f2bf(a.w);
    o[4] = f2bf(b.x); o[5] = f2bf(b.y); o[6] = f2bf(b.z); o[7] = f2bf(b.w);
}

__device__ __forceinline__ void cvt8(const float* __restrict__ p, bf16x8& o, float& sq) {
    float4 a = *(const float4*)p;
    float4 b = *(const float4*)(p + 4);
    cvt8r(a, b, o, sq);
}

// ---- lane ids ----
#define LANE_IDS()                                                             \
    const int tid = threadIdx.x;                                               \
    const int l   = tid & 63;                                                  \
    const int w   = tid >> 6;                                                  \
    const int c16 = l & 15;                                                    \
    const int g   = l >> 4;

// ---- B fragments + ||c||^2 in-register ----
#define PROLOGUE_B()                                                           \
    bf16x8 bfrag[NT][2];                                                       \
    float  cn2v[NT];                                                           \
    _Pragma("unroll")                                                          \
    for (int t = 0; t < NT; ++t) {                                             \
        int col = t * 16 + c16;                                                \
        bool valid = col < K_CL;                                               \
        float sq = 0.f;                                                        \
        _Pragma("unroll")                                                      \
        for (int kt = 0; kt < 2; ++kt) {                                       \
            bf16x8 bf;                                                         \
            if (valid) {                                                       \
                cvt8(cen + col * D_LAT + kt * 32 + g * 8, bf, sq);             \
            } else {                                                           \
                _Pragma("unroll")                                              \
                for (int i = 0; i < 8; ++i) bf[i] = 0;                         \
            }                                                                  \
            bfrag[t][kt] = bf;                                                 \
        }                                                                      \
        sq += __shfl_xor(sq, 16);                                              \
        sq += __shfl_xor(sq, 32);                                              \
        cn2v[t] = sq;                                                          \
    }                                                                          \
    const bool v6 = (c16 < 4); /* tile 6: cols 96..111, valid < 100 */

// ---- issue one group's enc loads into a named float4[4] ----
#define LOADS4(grp, A)                                                         \
    {                                                                          \
        const int rowbase_ = (grp) * 64 + w * 16;                              \
        const float* arow_ = enc + (size_t)(rowbase_ + c16) * D_LAT + g * 8;   \
        A[0] = *(const float4*)(arow_);                                        \
        A[1] = *(const float4*)(arow_ + 4);                                    \
        A[2] = *(const float4*)(arow_ + 32);                                   \
        A[3] = *(const float4*)(arow_ + 36);                                   \
    }

// ---- convert, MFMA dot, q + row-sums -> qv[NT][4], rs[4] (reads A[0..3]) ----
#define GROUP_COMPUTE_FROM(A)                                                  \
    float en2p = 0.f;                                                          \
    bf16x8 afrag0, afrag1;                                                     \
    cvt8r(A[0], A[1], afrag0, en2p);                                           \
    cvt8r(A[2], A[3], afrag1, en2p);                                           \
    en2p += __shfl_xor(en2p, 16);                                              \
    en2p += __shfl_xor(en2p, 32);                                              \
    f32x4 acc[NT];                                                             \
    _Pragma("unroll")                                                          \
    for (int t = 0; t < NT; ++t) {                                             \
        acc[t][0] = 0.f; acc[t][1] = 0.f; acc[t][2] = 0.f; acc[t][3] = 0.f;    \
    }                                                                          \
    _Pragma("unroll")                                                          \
    for (int t = 0; t < NT; ++t)                                               \
        acc[t] = __builtin_amdgcn_mfma_f32_16x16x32_bf16(afrag0, bfrag[t][0], acc[t], 0, 0, 0); \
    _Pragma("unroll")                                                          \
    for (int t = 0; t < NT; ++t)                                               \
        acc[t] = __builtin_amdgcn_mfma_f32_16x16x32_bf16(afrag1, bfrag[t][1], acc[t], 0, 0, 0); \
    float en2r[4];                                                             \
    _Pragma("unroll")                                                          \
    for (int r = 0; r < 4; ++r) en2r[r] = __shfl(en2p, g * 4 + r);             \
    float qv[NT][4];                                                           \
    float rs[4] = {0.f, 0.f, 0.f, 0.f};                                        \
    _Pragma("unroll")                                                          \
    for (int t = 0; t < NT; ++t) {                                             \
        _Pragma("unroll")                                                      \
        for (int r = 0; r < 4; ++r) {                                          \
            float d2 = en2r[r] + cn2v[t] - 2.f * acc[t][r];                    \
            float q = rcpf(1.f + fmaxf(d2, 0.f));                              \
            if (t == 6 && !v6) q = 0.f;                                        \
            qv[t][r] = q; rs[r] += q;                                          \
        }                                                                      \
    }                                                                          \
    _Pragma("unroll")                                                          \
    for (int r = 0; r < 4; ++r) {                                              \
        rs[r] += __shfl_xor(rs[r], 1); rs[r] += __shfl_xor(rs[r], 2);          \
        rs[r] += __shfl_xor(rs[r], 4); rs[r] += __shfl_xor(rs[r], 8);          \
        rs[r] = rcpf(rs[r]);                                                   \
    }

// ---- decoder-loss stream: ONE 32KB chunk per block, wave-level reduction ----
__device__ __forceinline__ void dec_stream(const f32x4* __restrict__ X,
                                           const f32x4* __restrict__ Dec,
                                           double* __restrict__ slots,
                                           int cidx) {
    const int idx = cidx * 2048 + (int)threadIdx.x;
    f32x4 a[8], b[8];
#pragma unroll
    for (int u = 0; u < 8; ++u) a[u] = X[idx + u * 256];
#pragma unroll
    for (int u = 0; u < 8; ++u) b[u] = Dec[idx + u * 256];
    __builtin_amdgcn_sched_barrier(0);   // pin: all 16 loads issued before use
    float local = 0.f;
#pragma unroll
    for (int u = 0; u < 8; ++u) {
        f32x4 d = a[u] - b[u];
        local = fmaf(d.x, d.x, local); local = fmaf(d.y, d.y, local);
        local = fmaf(d.z, d.z, local); local = fmaf(d.w, d.w, local);
    }
    // wave reduction: no LDS, no barriers
    local += __shfl_xor(local, 1);  local += __shfl_xor(local, 2);
    local += __shfl_xor(local, 4);  local += __shfl_xor(local, 8);
    local += __shfl_xor(local, 16); local += __shfl_xor(local, 32);
    if ((threadIdx.x & 63) == 0)
        atomicAdd(&slots[(cidx + (threadIdx.x >> 6)) & (NSLOT - 1)], (double)local);
}

// ---- dispatch 1: pass1 blocks [0,625) + one-chunk stream blocks [625, 625+3125) ----
__global__ void __launch_bounds__(TPB) k_d1(const f32x4* __restrict__ X,
                                            const f32x4* __restrict__ Xdec,
                                            const float* __restrict__ enc,
                                            const float* __restrict__ cen,
                                            double* __restrict__ dec_slots,
                                            float* __restrict__ fg) {
    if (blockIdx.x >= NMF) {
        dec_stream(X, Xdec, dec_slots, (int)blockIdx.x - NMF);
        return;
    }
    LANE_IDS();
    const int p1id = blockIdx.x;
    float4 abuf[2][4];
    LOADS4(p1id, abuf[0]);
    PROLOGUE_B();
    float facc[NT];
#pragma unroll
    for (int t = 0; t < NT; ++t) facc[t] = 0.f;
#pragma unroll
    for (int j = 0; j < GPB; ++j) {
        if (j + 1 < GPB) LOADS4(p1id + (j + 1) * NMF, abuf[(j + 1) & 1]);
        GROUP_COMPUTE_FROM(abuf[j & 1]);
#pragma unroll
        for (int t = 0; t < NT; ++t) {
            float a = 0.f;
#pragma unroll
            for (int r = 0; r < 4; ++r) a = fmaf(qv[t][r], rs[r], a);
            facc[t] += a;
        }
    }
    __shared__ float f_s[K_CL];
    for (int i = tid; i < K_CL; i += TPB) f_s[i] = 0.f;
    __syncthreads();
#pragma unroll
    for (int t = 0; t < NT; ++t) {
        float a = facc[t];
        a += __shfl_xor(a, 16);
        a += __shfl_xor(a, 32);
        int col = t * 16 + c16;
        if (g == 0 && col < K_CL) atomicAdd(&f_s[col], a);
    }
    __syncthreads();
    for (int i = tid; i < K_CL; i += TPB) atomicAdd(&fg[i], f_s[i]);
}

// ---- dispatch 2: pass2 blocks [0,625) + one-chunk stream blocks [625, 625+3125) ----
__global__ void __launch_bounds__(TPB) k_d2(const f32x4* __restrict__ X,
                                            const f32x4* __restrict__ Xdec,
                                            const float* __restrict__ enc,
                                            const float* __restrict__ cen,
                                            const float* __restrict__ fg,
                                            double* __restrict__ dec_slots,
                                            double* __restrict__ kl_slots) {
    if (blockIdx.x >= NMF) {
        dec_stream(X, Xdec, dec_slots, SC_HALF + (int)blockIdx.x - NMF);
        return;
    }
    LANE_IDS();
    const int p2id = blockIdx.x;
    float4 abuf[2][4];
    LOADS4(p2id, abuf[0]);
    PROLOGUE_B();
    float lfv[NT], rfv[NT];
#pragma unroll
    for (int t = 0; t < NT; ++t) {
        int col = t * 16 + c16;
        if (col < K_CL) {
            float fv = fg[col];
            lfv[t] = __logf(fv);
            rfv[t] = rcpf(fv);
        } else { lfv[t] = 0.f; rfv[t] = 0.f; }
    }
    float kl_local = 0.f;
#pragma unroll
    for (int j = 0; j < GPB; ++j) {
        if (j + 1 < GPB) LOADS4(p2id + (j + 1) * NMF, abuf[(j + 1) & 1]);
        GROUP_COMPUTE_FROM(abuf[j & 1]);
        float tac[4] = {0.f, 0.f, 0.f, 0.f};
        float Ap[4]  = {0.f, 0.f, 0.f, 0.f};
        float Bp[4]  = {0.f, 0.f, 0.f, 0.f};
#pragma unroll
        for (int t = 0; t < NT; ++t) {
#pragma unroll
            for (int r = 0; r < 4; ++r) {
                if (t == 6 && !v6) continue;      // masked col: q==0, avoid log(0)
                float q = qv[t][r] * rs[r];
                float pu = q * q * rfv[t];
                tac[r] += pu;
                Ap[r] = fmaf(pu, __logf(q), Ap[r]);
                Bp[r] = fmaf(pu, lfv[t], Bp[r]);
            }
        }
#pragma unroll
        for (int r = 0; r < 4; ++r) {
            tac[r] += __shfl_xor(tac[r], 1); tac[r] += __shfl_xor(tac[r], 2);
            tac[r] += __shfl_xor(tac[r], 4); tac[r] += __shfl_xor(tac[r], 8);
            Ap[r]  += __shfl_xor(Ap[r], 1);  Ap[r]  += __shfl_xor(Ap[r], 2);
            Ap[r]  += __shfl_xor(Ap[r], 4);  Ap[r]  += __shfl_xor(Ap[r], 8);
            Bp[r]  += __shfl_xor(Bp[r], 1);  Bp[r]  += __shfl_xor(Bp[r], 2);
            Bp[r]  += __shfl_xor(Bp[r], 4);  Bp[r]  += __shfl_xor(Bp[r], 8);
        }
        if (c16 == 0) {
#pragma unroll
            for (int r = 0; r < 4; ++r)
                kl_local += (Ap[r] - Bp[r]) * rcpf(tac[r]) - __logf(tac[r]);
        }
    }
    __shared__ float red[TPB];
    red[tid] = kl_local;
    __syncthreads();
    for (int off = TPB / 2; off > 0; off >>= 1) {
        if (tid < off) red[tid] += red[tid + off];
        __syncthreads();
    }
    if (tid == 0) atomicAdd(&kl_slots[p2id & (NSLOT - 1)], (double)red[0]);
}

__global__ void k_final(const double* __restrict__ dec_s,
                        const double* __restrict__ kl_s,
                        float* __restrict__ out) {
    int l = threadIdx.x;     // 64 threads = one wave
    double d = dec_s[l];
    double k = kl_s[l];
#pragma unroll
    for (int off = 32; off > 0; off >>= 1) {
        d += __shfl_xor(d, off);
        k += __shfl_xor(k, off);
    }
    if (l == 0)
        out[0] = (float)(d / ((double)N_ROWS * (double)D_IN) + 1000.0 * (k / (double)N_ROWS));
}

extern "C" void kernel_launch(void* const* d_in, const int* in_sizes, int n_in,
                              void* d_out, int out_size, void* d_ws, size_t ws_size,
                              hipStream_t stream) {
    (void)in_sizes; (void)n_in; (void)out_size; (void)ws_size;
    const float* X   = (const float*)d_in[0];
    const float* enc = (const float*)d_in[1];
    const float* dec = (const float*)d_in[2];
    const float* cen = (const float*)d_in[3];
    float* out = (float*)d_out;

    double* dec_slots = (double*)d_ws;                       // 64 doubles
    double* kl_slots  = (double*)((char*)d_ws + 512);        // 64 doubles
    float*  fg        = (float*)((char*)d_ws + 1024);        // 128 floats

    hipMemsetAsync(d_ws, 0, 1536, stream);
    k_d1<<<NMF + SC_HALF, TPB, 0, stream>>>(
        (const f32x4*)X, (const f32x4*)dec, enc, cen, dec_slots, fg);
    k_d2<<<NMF + SC_HALF, TPB, 0, stream>>>(
        (const f32x4*)X, (const f32x4*)dec, enc, cen, fg, dec_slots, kl_slots);
    k_final<<<1, 64, 0, stream>>>(dec_slots, kl_slots, out);
}

// Round 11
// 143.694 us; speedup vs baseline: 1.2280x; 1.0133x over previous
//
#include <hip/hip_runtime.h>

#define N_ROWS 200000
#define D_IN   256
#define D_LAT  64
#define K_CL   100
#define NT     7            // 7 cluster tiles of 16 -> 112 (cols >=100 masked)
#define TPB    256

#define GRPS   3125         // row groups of 64 (4 waves x 16 rows)
#define NMF    625          // MFMA blocks per dispatch
#define GPB    5            // groups per MFMA block (3125/625)

// stream geometry: 12.8e6 float4s per array; per dispatch half = 6.4e6 float4s
// chunk = 1024 float4s per array (4/thread) -> NCH = 6250 chunks per dispatch
#define NCH    6250
#define NSTR   1024         // persistent stream blocks per dispatch (4 blocks/CU)

typedef __attribute__((ext_vector_type(8))) short bf16x8;
typedef __attribute__((ext_vector_type(4))) float f32x4;

__device__ __forceinline__ float rcpf(float x) { return __builtin_amdgcn_rcpf(x); }

__device__ __forceinline__ short f2bf(float f) {
    union { float f; unsigned u; } v; v.f = f;
    unsigned r = (v.u + 0x7fffu + ((v.u >> 16) & 1u)) >> 16;
    return (short)r;
}

__device__ __forceinline__ void cvt8r(float4 a, float4 b, bf16x8& o, float& sq) {
    sq = fmaf(a.x, a.x, sq); sq = fmaf(a.y, a.y, sq);
    sq = fmaf(a.z, a.z, sq); sq = fmaf(a.w, a.w, sq);
    sq = fmaf(b.x, b.x, sq); sq = fmaf(b.y, b.y, sq);
    sq = fmaf(b.z, b.z, sq); sq = fmaf(b.w, b.w, sq);
    o[0] = f2bf(a.x); o[1] = f2bf(a.y); o[2] = f2bf(a.z); o[3] = f2bf(a.w);
    o[4] = f2bf(b.x); o[5] = f2bf(b.y); o[6] = f2bf(b.z); o[7] = f2bf(b.w);
}

__device__ __forceinline__ void cvt8(const float* __restrict__ p, bf16x8& o, float& sq) {
    float4 a = *(const float4*)p;
    float4 b = *(const float4*)(p + 4);
    cvt8r(a, b, o, sq);
}

// ---- lane ids ----
#define LANE_IDS()                                                             \
    const int tid = threadIdx.x;                                               \
    const int l   = tid & 63;                                                  \
    const int w   = tid >> 6;                                                  \
    const int c16 = l & 15;                                                    \
    const int g   = l >> 4;

// ---- B fragments + ||c||^2 in-register ----
#define PROLOGUE_B()                                                           \
    bf16x8 bfrag[NT][2];                                                       \
    float  cn2v[NT];                                                           \
    _Pragma("unroll")                                                          \
    for (int t = 0; t < NT; ++t) {                                             \
        int col = t * 16 + c16;                                                \
        bool valid = col < K_CL;                                               \
        float sq = 0.f;                                                        \
        _Pragma("unroll")                                                      \
        for (int kt = 0; kt < 2; ++kt) {                                       \
            bf16x8 bf;                                                         \
            if (valid) {                                                       \
                cvt8(cen + col * D_LAT + kt * 32 + g * 8, bf, sq);             \
            } else {                                                           \
                _Pragma("unroll")                                              \
                for (int i = 0; i < 8; ++i) bf[i] = 0;                         \
            }                                                                  \
            bfrag[t][kt] = bf;                                                 \
        }                                                                      \
        sq += __shfl_xor(sq, 16);                                              \
        sq += __shfl_xor(sq, 32);                                              \
        cn2v[t] = sq;                                                          \
    }                                                                          \
    const bool v6 = (c16 < 4); /* tile 6: cols 96..111, valid < 100 */

// ---- issue one group's enc loads into a named float4[4] ----
#define LOADS4(grp, A)                                                         \
    {                                                                          \
        const int rowbase_ = (grp) * 64 + w * 16;                              \
        const float* arow_ = enc + (size_t)(rowbase_ + c16) * D_LAT + g * 8;   \
        A[0] = *(const float4*)(arow_);                                        \
        A[1] = *(const float4*)(arow_ + 4);                                    \
        A[2] = *(const float4*)(arow_ + 32);                                   \
        A[3] = *(const float4*)(arow_ + 36);                                   \
    }

// ---- convert, MFMA dot, q + row-sums -> qv[NT][4], rs[4] (reads A[0..3]) ----
#define GROUP_COMPUTE_FROM(A)                                                  \
    float en2p = 0.f;                                                          \
    bf16x8 afrag0, afrag1;                                                     \
    cvt8r(A[0], A[1], afrag0, en2p);                                           \
    cvt8r(A[2], A[3], afrag1, en2p);                                           \
    en2p += __shfl_xor(en2p, 16);                                              \
    en2p += __shfl_xor(en2p, 32);                                              \
    f32x4 acc[NT];                                                             \
    _Pragma("unroll")                                                          \
    for (int t = 0; t < NT; ++t) {                                             \
        acc[t][0] = 0.f; acc[t][1] = 0.f; acc[t][2] = 0.f; acc[t][3] = 0.f;    \
    }                                                                          \
    _Pragma("unroll")                                                          \
    for (int t = 0; t < NT; ++t)                                               \
        acc[t] = __builtin_amdgcn_mfma_f32_16x16x32_bf16(afrag0, bfrag[t][0], acc[t], 0, 0, 0); \
    _Pragma("unroll")                                                          \
    for (int t = 0; t < NT; ++t)                                               \
        acc[t] = __builtin_amdgcn_mfma_f32_16x16x32_bf16(afrag1, bfrag[t][1], acc[t], 0, 0, 0); \
    float en2r[4];                                                             \
    _Pragma("unroll")                                                          \
    for (int r = 0; r < 4; ++r) en2r[r] = __shfl(en2p, g * 4 + r);             \
    float qv[NT][4];                                                           \
    float rs[4] = {0.f, 0.f, 0.f, 0.f};                                        \
    _Pragma("unroll")                                                          \
    for (int t = 0; t < NT; ++t) {                                             \
        _Pragma("unroll")                                                      \
        for (int r = 0; r < 4; ++r) {                                          \
            float d2 = en2r[r] + cn2v[t] - 2.f * acc[t][r];                    \
            float q = rcpf(1.f + fmaxf(d2, 0.f));                              \
            if (t == 6 && !v6) q = 0.f;                                        \
            qv[t][r] = q; rs[r] += q;                                          \
        }                                                                      \
    }                                                                          \
    _Pragma("unroll")                                                          \
    for (int r = 0; r < 4; ++r) {                                              \
        rs[r] += __shfl_xor(rs[r], 1); rs[r] += __shfl_xor(rs[r], 2);          \
        rs[r] += __shfl_xor(rs[r], 4); rs[r] += __shfl_xor(rs[r], 8);          \
        rs[r] = rcpf(rs[r]);                                                   \
    }

// ---- decoder-loss stream: persistent, 2-stage software-pipelined, no atomics ----
__device__ __forceinline__ void dec_stream(const f32x4* __restrict__ X,
                                           const f32x4* __restrict__ Dec,
                                           double* __restrict__ slots,
                                           int sid, int cbase, int slotbase) {
    const int tid = (int)threadIdx.x;
    float local = 0.f;
    f32x4 a0[4], b0[4], a1[4], b1[4];
    int c = sid;
    {
        const int idx = (cbase + c) * 1024 + tid;
#pragma unroll
        for (int u = 0; u < 4; ++u) a0[u] = X[idx + u * 256];
#pragma unroll
        for (int u = 0; u < 4; ++u) b0[u] = Dec[idx + u * 256];
    }
#pragma unroll 1
    while (true) {
        const int c1 = c + NSTR;
        if (c1 < NCH) {
            const int idx1 = (cbase + c1) * 1024 + tid;
#pragma unroll
            for (int u = 0; u < 4; ++u) a1[u] = X[idx1 + u * 256];
#pragma unroll
            for (int u = 0; u < 4; ++u) b1[u] = Dec[idx1 + u * 256];
        }
        __builtin_amdgcn_sched_barrier(0);   // next-stage loads issued before this compute
#pragma unroll
        for (int u = 0; u < 4; ++u) {
            f32x4 d = a0[u] - b0[u];
            local = fmaf(d.x, d.x, local); local = fmaf(d.y, d.y, local);
            local = fmaf(d.z, d.z, local); local = fmaf(d.w, d.w, local);
        }
        if (c1 >= NCH) break;
        const int c2 = c1 + NSTR;
        if (c2 < NCH) {
            const int idx2 = (cbase + c2) * 1024 + tid;
#pragma unroll
            for (int u = 0; u < 4; ++u) a0[u] = X[idx2 + u * 256];
#pragma unroll
            for (int u = 0; u < 4; ++u) b0[u] = Dec[idx2 + u * 256];
        }
        __builtin_amdgcn_sched_barrier(0);
#pragma unroll
        for (int u = 0; u < 4; ++u) {
            f32x4 d = a1[u] - b1[u];
            local = fmaf(d.x, d.x, local); local = fmaf(d.y, d.y, local);
            local = fmaf(d.z, d.z, local); local = fmaf(d.w, d.w, local);
        }
        if (c2 >= NCH) break;
        c = c2;
    }
    // wave reduction, no LDS, no barriers; plain store to unique per-wave slot
    local += __shfl_xor(local, 1);  local += __shfl_xor(local, 2);
    local += __shfl_xor(local, 4);  local += __shfl_xor(local, 8);
    local += __shfl_xor(local, 16); local += __shfl_xor(local, 32);
    if ((tid & 63) == 0)
        slots[slotbase + sid * 4 + (tid >> 6)] = (double)local;
}

// ---- dispatch 1: pass1 blocks [0,625) + pipelined stream blocks [625, 625+1024) ----
__global__ void __launch_bounds__(TPB) k_d1(const f32x4* __restrict__ X,
                                            const f32x4* __restrict__ Xdec,
                                            const float* __restrict__ enc,
                                            const float* __restrict__ cen,
                                            double* __restrict__ dec_slots,
                                            float* __restrict__ fg) {
    if (blockIdx.x >= NMF) {
        dec_stream(X, Xdec, dec_slots, (int)blockIdx.x - NMF, 0, 0);
        return;
    }
    LANE_IDS();
    const int p1id = blockIdx.x;
    float4 abuf[2][4];
    LOADS4(p1id, abuf[0]);
    PROLOGUE_B();
    float facc[NT];
#pragma unroll
    for (int t = 0; t < NT; ++t) facc[t] = 0.f;
#pragma unroll
    for (int j = 0; j < GPB; ++j) {
        if (j + 1 < GPB) LOADS4(p1id + (j + 1) * NMF, abuf[(j + 1) & 1]);
        GROUP_COMPUTE_FROM(abuf[j & 1]);
#pragma unroll
        for (int t = 0; t < NT; ++t) {
            float a = 0.f;
#pragma unroll
            for (int r = 0; r < 4; ++r) a = fmaf(qv[t][r], rs[r], a);
            facc[t] += a;
        }
    }
    __shared__ float f_s[K_CL];
    for (int i = tid; i < K_CL; i += TPB) f_s[i] = 0.f;
    __syncthreads();
#pragma unroll
    for (int t = 0; t < NT; ++t) {
        float a = facc[t];
        a += __shfl_xor(a, 16);
        a += __shfl_xor(a, 32);
        int col = t * 16 + c16;
        if (g == 0 && col < K_CL) atomicAdd(&f_s[col], a);
    }
    __syncthreads();
    for (int i = tid; i < K_CL; i += TPB) atomicAdd(&fg[i], f_s[i]);
}

// ---- dispatch 2: pass2 blocks [0,625) + pipelined stream blocks [625, 625+1024) ----
__global__ void __launch_bounds__(TPB) k_d2(const f32x4* __restrict__ X,
                                            const f32x4* __restrict__ Xdec,
                                            const float* __restrict__ enc,
                                            const float* __restrict__ cen,
                                            const float* __restrict__ fg,
                                            double* __restrict__ dec_slots,
                                            double* __restrict__ kl_slots) {
    if (blockIdx.x >= NMF) {
        dec_stream(X, Xdec, dec_slots, (int)blockIdx.x - NMF, NCH, NSTR * 4);
        return;
    }
    LANE_IDS();
    const int p2id = blockIdx.x;
    float4 abuf[2][4];
    LOADS4(p2id, abuf[0]);
    PROLOGUE_B();
    float lfv[NT], rfv[NT];
#pragma unroll
    for (int t = 0; t < NT; ++t) {
        int col = t * 16 + c16;
        if (col < K_CL) {
            float fv = fg[col];
            lfv[t] = __logf(fv);
            rfv[t] = rcpf(fv);
        } else { lfv[t] = 0.f; rfv[t] = 0.f; }
    }
    float kl_local = 0.f;
#pragma unroll
    for (int j = 0; j < GPB; ++j) {
        if (j + 1 < GPB) LOADS4(p2id + (j + 1) * NMF, abuf[(j + 1) & 1]);
        GROUP_COMPUTE_FROM(abuf[j & 1]);
        float tac[4] = {0.f, 0.f, 0.f, 0.f};
        float Ap[4]  = {0.f, 0.f, 0.f, 0.f};
        float Bp[4]  = {0.f, 0.f, 0.f, 0.f};
#pragma unroll
        for (int t = 0; t < NT; ++t) {
#pragma unroll
            for (int r = 0; r < 4; ++r) {
                if (t == 6 && !v6) continue;      // masked col: q==0, avoid log(0)
                float q = qv[t][r] * rs[r];
                float pu = q * q * rfv[t];
                tac[r] += pu;
                Ap[r] = fmaf(pu, __logf(q), Ap[r]);
                Bp[r] = fmaf(pu, lfv[t], Bp[r]);
            }
        }
#pragma unroll
        for (int r = 0; r < 4; ++r) {
            tac[r] += __shfl_xor(tac[r], 1); tac[r] += __shfl_xor(tac[r], 2);
            tac[r] += __shfl_xor(tac[r], 4); tac[r] += __shfl_xor(tac[r], 8);
            Ap[r]  += __shfl_xor(Ap[r], 1);  Ap[r]  += __shfl_xor(Ap[r], 2);
            Ap[r]  += __shfl_xor(Ap[r], 4);  Ap[r]  += __shfl_xor(Ap[r], 8);
            Bp[r]  += __shfl_xor(Bp[r], 1);  Bp[r]  += __shfl_xor(Bp[r], 2);
            Bp[r]  += __shfl_xor(Bp[r], 4);  Bp[r]  += __shfl_xor(Bp[r], 8);
        }
        if (c16 == 0) {
#pragma unroll
            for (int r = 0; r < 4; ++r)
                kl_local += (Ap[r] - Bp[r]) * rcpf(tac[r]) - __logf(tac[r]);
        }
    }
    __shared__ float red[TPB];
    red[tid] = kl_local;
    __syncthreads();
    for (int off = TPB / 2; off > 0; off >>= 1) {
        if (tid < off) red[tid] += red[tid + off];
        __syncthreads();
    }
    if (tid == 0) kl_slots[p2id] = (double)red[0];   // unique slot, plain store
}

__global__ void k_final(const double* __restrict__ dec_s,
                        const double* __restrict__ kl_s,
                        float* __restrict__ out) {
    __shared__ double rd[256], rk[256];
    const int t = threadIdx.x;
    double d = 0.0, k = 0.0;
    for (int i = t; i < NSTR * 8; i += 256) d += dec_s[i];
    for (int i = t; i < NMF; i += 256) k += kl_s[i];
    rd[t] = d; rk[t] = k;
    __syncthreads();
    for (int off = 128; off > 0; off >>= 1) {
        if (t < off) { rd[t] += rd[t + off]; rk[t] += rk[t + off]; }
        __syncthreads();
    }
    if (t == 0)
        out[0] = (float)(rd[0] / ((double)N_ROWS * (double)D_IN)
                         + 1000.0 * (rk[0] / (double)N_ROWS));
}

extern "C" void kernel_launch(void* const* d_in, const int* in_sizes, int n_in,
                              void* d_out, int out_size, void* d_ws, size_t ws_size,
                              hipStream_t stream) {
    (void)in_sizes; (void)n_in; (void)out_size; (void)ws_size;
    const float* X   = (const float*)d_in[0];
    const float* enc = (const float*)d_in[1];
    const float* dec = (const float*)d_in[2];
    const float* cen = (const float*)d_in[3];
    float* out = (float*)d_out;

    double* dec_slots = (double*)d_ws;                        // 8192 doubles (64 KB)
    double* kl_slots  = (double*)((char*)d_ws + 65536);       // 625 doubles
    float*  fg        = (float*)((char*)d_ws + 73728);        // 128 floats

    hipMemsetAsync((char*)d_ws + 73728, 0, 512, stream);      // only fg needs zeroing
    k_d1<<<NMF + NSTR, TPB, 0, stream>>>(
        (const f32x4*)X, (const f32x4*)dec, enc, cen, dec_slots, fg);
    k_d2<<<NMF + NSTR, TPB, 0, stream>>>(
        (const f32x4*)X, (const f32x4*)dec, enc, cen, fg, dec_slots, kl_slots);
    k_final<<<1, 256, 0, stream>>>(dec_slots, kl_slots, out);
}

// Round 12
// 132.984 us; speedup vs baseline: 1.3269x; 1.0805x over previous
//
#include <hip/hip_runtime.h>

#define N_ROWS 200000
#define D_IN   256
#define D_LAT  64
#define K_CL   100
#define NT     7            // 7 cluster tiles of 16 -> 112 (cols >=100 masked)
#define TPB    256

#define GRPS   3125         // row groups of 64 (4 waves x 16 rows)
#define NMF    625          // MFMA blocks per dispatch
#define GPB    5            // groups per MFMA block (3125/625)

// stream geometry: 12.8e6 float4s per array = 6250 chunks of 2048 (32 KB/array)
#define SC_HALF   3125      // chunks per dispatch
#define NSTR      768       // persistent stream blocks per dispatch (R7 had 512)
#define NSLOT     64

typedef __attribute__((ext_vector_type(8))) short bf16x8;
typedef __attribute__((ext_vector_type(4))) float f32x4;

__device__ __forceinline__ float rcpf(float x) { return __builtin_amdgcn_rcpf(x); }

__device__ __forceinline__ short f2bf(float f) {
    union { float f; unsigned u; } v; v.f = f;
    unsigned r = (v.u + 0x7fffu + ((v.u >> 16) & 1u)) >> 16;
    return (short)r;
}

__device__ __forceinline__ void cvt8r(float4 a, float4 b, bf16x8& o, float& sq) {
    sq = fmaf(a.x, a.x, sq); sq = fmaf(a.y, a.y, sq);
    sq = fmaf(a.z, a.z, sq); sq = fmaf(a.w, a.w, sq);
    sq = fmaf(b.x, b.x, sq); sq = fmaf(b.y, b.y, sq);
    sq = fmaf(b.z, b.z, sq); sq = fmaf(b.w, b.w, sq);
    o[0] = f2bf(a.x); o[1] = f2bf(a.y); o[2] = f2bf(a.z); o[3] = f2bf(a.w);
    o[4] = f2bf(b.x); o[5] = f2bf(b.y); o[6] = f2bf(b.z); o[7] = f2bf(b.w);
}

__device__ __forceinline__ void cvt8(const float* __restrict__ p, bf16x8& o, float& sq) {
    float4 a = *(const float4*)p;
    float4 b = *(const float4*)(p + 4);
    cvt8r(a, b, o, sq);
}

// ---- lane ids ----
#define LANE_IDS()                                                             \
    const int tid = threadIdx.x;                                               \
    const int l   = tid & 63;                                                  \
    const int w   = tid >> 6;                                                  \
    const int c16 = l & 15;                                                    \
    const int g   = l >> 4;

// ---- B fragments + ||c||^2 in-register ----
#define PROLOGUE_B()                                                           \
    bf16x8 bfrag[NT][2];                                                       \
    float  cn2v[NT];                                                           \
    _Pragma("unroll")                                                          \
    for (int t = 0; t < NT; ++t) {                                             \
        int col = t * 16 + c16;                                                \
        bool valid = col < K_CL;                                               \
        float sq = 0.f;                                                        \
        _Pragma("unroll")                                                      \
        for (int kt = 0; kt < 2; ++kt) {                                       \
            bf16x8 bf;                                                         \
            if (valid) {                                                       \
                cvt8(cen + col * D_LAT + kt * 32 + g * 8, bf, sq);             \
            } else {                                                           \
                _Pragma("unroll")                                              \
                for (int i = 0; i < 8; ++i) bf[i] = 0;                         \
            }                                                                  \
            bfrag[t][kt] = bf;                                                 \
        }                                                                      \
        sq += __shfl_xor(sq, 16);                                              \
        sq += __shfl_xor(sq, 32);                                              \
        cn2v[t] = sq;                                                          \
    }                                                                          \
    const bool v6 = (c16 < 4); /* tile 6: cols 96..111, valid < 100 */

// ---- issue one group's enc loads into a named float4[4] ----
#define LOADS4(grp, A)                                                         \
    {                                                                          \
        const int rowbase_ = (grp) * 64 + w * 16;                              \
        const float* arow_ = enc + (size_t)(rowbase_ + c16) * D_LAT + g * 8;   \
        A[0] = *(const float4*)(arow_);                                        \
        A[1] = *(const float4*)(arow_ + 4);                                    \
        A[2] = *(const float4*)(arow_ + 32);                                   \
        A[3] = *(const float4*)(arow_ + 36);                                   \
    }

// ---- convert, MFMA dot, q + row-sums -> qv[NT][4], rs[4] (reads A[0..3]) ----
#define GROUP_COMPUTE_FROM(A)                                                  \
    float en2p = 0.f;                                                          \
    bf16x8 afrag0, afrag1;                                                     \
    cvt8r(A[0], A[1], afrag0, en2p);                                           \
    cvt8r(A[2], A[3], afrag1, en2p);                                           \
    en2p += __shfl_xor(en2p, 16);                                              \
    en2p += __shfl_xor(en2p, 32);                                              \
    f32x4 acc[NT];                                                             \
    _Pragma("unroll")                                                          \
    for (int t = 0; t < NT; ++t) {                                             \
        acc[t][0] = 0.f; acc[t][1] = 0.f; acc[t][2] = 0.f; acc[t][3] = 0.f;    \
    }                                                                          \
    _Pragma("unroll")                                                          \
    for (int t = 0; t < NT; ++t)                                               \
        acc[t] = __builtin_amdgcn_mfma_f32_16x16x32_bf16(afrag0, bfrag[t][0], acc[t], 0, 0, 0); \
    _Pragma("unroll")                                                          \
    for (int t = 0; t < NT; ++t)                                               \
        acc[t] = __builtin_amdgcn_mfma_f32_16x16x32_bf16(afrag1, bfrag[t][1], acc[t], 0, 0, 0); \
    float en2r[4];                                                             \
    _Pragma("unroll")                                                          \
    for (int r = 0; r < 4; ++r) en2r[r] = __shfl(en2p, g * 4 + r);             \
    float qv[NT][4];                                                           \
    float rs[4] = {0.f, 0.f, 0.f, 0.f};                                        \
    _Pragma("unroll")                                                          \
    for (int t = 0; t < NT; ++t) {                                             \
        _Pragma("unroll")                                                      \
        for (int r = 0; r < 4; ++r) {                                          \
            float d2 = en2r[r] + cn2v[t] - 2.f * acc[t][r];                    \
            float q = rcpf(1.f + fmaxf(d2, 0.f));                              \
            if (t == 6 && !v6) q = 0.f;                                        \
            qv[t][r] = q; rs[r] += q;                                          \
        }                                                                      \
    }                                                                          \
    _Pragma("unroll")                                                          \
    for (int r = 0; r < 4; ++r) {                                              \
        rs[r] += __shfl_xor(rs[r], 1); rs[r] += __shfl_xor(rs[r], 2);          \
        rs[r] += __shfl_xor(rs[r], 4); rs[r] += __shfl_xor(rs[r], 8);          \
        rs[r] = rcpf(rs[r]);                                                   \
    }

// ---- decoder-loss stream: persistent blocks, 16 loads in flight (R7 structure) ----
__device__ __forceinline__ void dec_stream(const f32x4* __restrict__ X,
                                           const f32x4* __restrict__ Dec,
                                           double* __restrict__ slots,
                                           int sid, int cbase) {
    float local = 0.f;
#pragma unroll 1
    for (int c = sid; c < SC_HALF; c += NSTR) {
        const int idx = (cbase + c) * 2048 + (int)threadIdx.x;
        f32x4 a[8], b[8];
#pragma unroll
        for (int u = 0; u < 8; ++u)
            a[u] = __builtin_nontemporal_load(X + idx + u * 256);
#pragma unroll
        for (int u = 0; u < 8; ++u)
            b[u] = __builtin_nontemporal_load(Dec + idx + u * 256);
        __builtin_amdgcn_sched_barrier(0);   // pin: all 16 loads issued before use
#pragma unroll
        for (int u = 0; u < 8; ++u) {
            f32x4 d = a[u] - b[u];
            local = fmaf(d.x, d.x, local); local = fmaf(d.y, d.y, local);
            local = fmaf(d.z, d.z, local); local = fmaf(d.w, d.w, local);
        }
    }
    __shared__ float red[TPB];
    red[threadIdx.x] = local;
    __syncthreads();
    for (int off = TPB / 2; off > 0; off >>= 1) {
        if (threadIdx.x < off) red[threadIdx.x] += red[threadIdx.x + off];
        __syncthreads();
    }
    if (threadIdx.x == 0) atomicAdd(&slots[sid & (NSLOT - 1)], (double)red[0]);
}

// ---- dispatch 1: pass1 blocks [0,625) + persistent stream blocks [625, 625+NSTR) ----
__global__ void __launch_bounds__(TPB) k_d1(const f32x4* __restrict__ X,
                                            const f32x4* __restrict__ Xdec,
                                            const float* __restrict__ enc,
                                            const float* __restrict__ cen,
                                            double* __restrict__ dec_slots,
                                            float* __restrict__ fg) {
    if (blockIdx.x >= NMF) {
        dec_stream(X, Xdec, dec_slots, (int)blockIdx.x - NMF, 0);
        return;
    }
    LANE_IDS();
    const int p1id = blockIdx.x;
    float4 abuf[2][4];
    LOADS4(p1id, abuf[0]);
    PROLOGUE_B();
    float facc[NT];
#pragma unroll
    for (int t = 0; t < NT; ++t) facc[t] = 0.f;
#pragma unroll
    for (int j = 0; j < GPB; ++j) {
        if (j + 1 < GPB) LOADS4(p1id + (j + 1) * NMF, abuf[(j + 1) & 1]);
        GROUP_COMPUTE_FROM(abuf[j & 1]);
#pragma unroll
        for (int t = 0; t < NT; ++t) {
            float a = 0.f;
#pragma unroll
            for (int r = 0; r < 4; ++r) a = fmaf(qv[t][r], rs[r], a);
            facc[t] += a;
        }
    }
    __shared__ float f_s[K_CL];
    for (int i = tid; i < K_CL; i += TPB) f_s[i] = 0.f;
    __syncthreads();
#pragma unroll
    for (int t = 0; t < NT; ++t) {
        float a = facc[t];
        a += __shfl_xor(a, 16);
        a += __shfl_xor(a, 32);
        int col = t * 16 + c16;
        if (g == 0 && col < K_CL) atomicAdd(&f_s[col], a);
    }
    __syncthreads();
    for (int i = tid; i < K_CL; i += TPB) atomicAdd(&fg[i], f_s[i]);
}

// ---- dispatch 2: pass2 blocks [0,625) + persistent stream blocks [625, 625+NSTR) ----
__global__ void __launch_bounds__(TPB) k_d2(const f32x4* __restrict__ X,
                                            const f32x4* __restrict__ Xdec,
                                            const float* __restrict__ enc,
                                            const float* __restrict__ cen,
                                            const float* __restrict__ fg,
                                            double* __restrict__ dec_slots,
                                            double* __restrict__ kl_slots) {
    if (blockIdx.x >= NMF) {
        dec_stream(X, Xdec, dec_slots, (int)blockIdx.x - NMF, SC_HALF);
        return;
    }
    LANE_IDS();
    const int p2id = blockIdx.x;
    float4 abuf[2][4];
    LOADS4(p2id, abuf[0]);
    PROLOGUE_B();
    float lfv[NT], rfv[NT];
#pragma unroll
    for (int t = 0; t < NT; ++t) {
        int col = t * 16 + c16;
        if (col < K_CL) {
            float fv = fg[col];
            lfv[t] = __logf(fv);
            rfv[t] = rcpf(fv);
        } else { lfv[t] = 0.f; rfv[t] = 0.f; }
    }
    float kl_local = 0.f;
#pragma unroll
    for (int j = 0; j < GPB; ++j) {
        if (j + 1 < GPB) LOADS4(p2id + (j + 1) * NMF, abuf[(j + 1) & 1]);
        GROUP_COMPUTE_FROM(abuf[j & 1]);
        float tac[4] = {0.f, 0.f, 0.f, 0.f};
        float Ap[4]  = {0.f, 0.f, 0.f, 0.f};
        float Bp[4]  = {0.f, 0.f, 0.f, 0.f};
#pragma unroll
        for (int t = 0; t < NT; ++t) {
#pragma unroll
            for (int r = 0; r < 4; ++r) {
                if (t == 6 && !v6) continue;      // masked col: q==0, avoid log(0)
                float q = qv[t][r] * rs[r];
                float pu = q * q * rfv[t];
                tac[r] += pu;
                Ap[r] = fmaf(pu, __logf(q), Ap[r]);
                Bp[r] = fmaf(pu, lfv[t], Bp[r]);
            }
        }
#pragma unroll
        for (int r = 0; r < 4; ++r) {
            tac[r] += __shfl_xor(tac[r], 1); tac[r] += __shfl_xor(tac[r], 2);
            tac[r] += __shfl_xor(tac[r], 4); tac[r] += __shfl_xor(tac[r], 8);
            Ap[r]  += __shfl_xor(Ap[r], 1);  Ap[r]  += __shfl_xor(Ap[r], 2);
            Ap[r]  += __shfl_xor(Ap[r], 4);  Ap[r]  += __shfl_xor(Ap[r], 8);
            Bp[r]  += __shfl_xor(Bp[r], 1);  Bp[r]  += __shfl_xor(Bp[r], 2);
            Bp[r]  += __shfl_xor(Bp[r], 4);  Bp[r]  += __shfl_xor(Bp[r], 8);
        }
        if (c16 == 0) {
#pragma unroll
            for (int r = 0; r < 4; ++r)
                kl_local += (Ap[r] - Bp[r]) * rcpf(tac[r]) - __logf(tac[r]);
        }
    }
    __shared__ float red[TPB];
    red[tid] = kl_local;
    __syncthreads();
    for (int off = TPB / 2; off > 0; off >>= 1) {
        if (tid < off) red[tid] += red[tid + off];
        __syncthreads();
    }
    if (tid == 0) atomicAdd(&kl_slots[p2id & (NSLOT - 1)], (double)red[0]);
}

__global__ void k_final(const double* __restrict__ dec_s,
                        const double* __restrict__ kl_s,
                        float* __restrict__ out) {
    int l = threadIdx.x;     // 64 threads = one wave
    double d = dec_s[l];
    double k = kl_s[l];
#pragma unroll
    for (int off = 32; off > 0; off >>= 1) {
        d += __shfl_xor(d, off);
        k += __shfl_xor(k, off);
    }
    if (l == 0)
        out[0] = (float)(d / ((double)N_ROWS * (double)D_IN) + 1000.0 * (k / (double)N_ROWS));
}

extern "C" void kernel_launch(void* const* d_in, const int* in_sizes, int n_in,
                              void* d_out, int out_size, void* d_ws, size_t ws_size,
                              hipStream_t stream) {
    (void)in_sizes; (void)n_in; (void)out_size; (void)ws_size;
    const float* X   = (const float*)d_in[0];
    const float* enc = (const float*)d_in[1];
    const float* dec = (const float*)d_in[2];
    const float* cen = (const float*)d_in[3];
    float* out = (float*)d_out;

    double* dec_slots = (double*)d_ws;                       // 64 doubles
    double* kl_slots  = (double*)((char*)d_ws + 512);        // 64 doubles
    float*  fg        = (float*)((char*)d_ws + 1024);        // 128 floats

    hipMemsetAsync(d_ws, 0, 1536, stream);
    k_d1<<<NMF + NSTR, TPB, 0, stream>>>(
        (const f32x4*)X, (const f32x4*)dec, enc, cen, dec_slots, fg);
    k_d2<<<NMF + NSTR, TPB, 0, stream>>>(
        (const f32x4*)X, (const f32x4*)dec, enc, cen, fg, dec_slots, kl_slots);
    k_final<<<1, 64, 0, stream>>>(dec_slots, kl_slots, out);
}

// Round 14
// 132.577 us; speedup vs baseline: 1.3310x; 1.0031x over previous
//
#include <hip/hip_runtime.h>

#define N_ROWS 200000
#define D_IN   256
#define D_LAT  64
#define K_CL   100
#define NT     7            // 7 cluster tiles of 16 -> 112 (cols >=100 masked)
#define TPB    256

#define GRPS   3125         // row groups of 64 (4 waves x 16 rows)
#define NMF    625          // MFMA blocks per dispatch
#define GPB    5            // groups per MFMA block (3125/625)

// stream geometry: 12.8e6 float4s per array = 6250 chunks of 2048 (32 KB/array)
#define SC_HALF   3125      // chunks per dispatch
#define NSTR      768       // persistent stream blocks per dispatch
#define NSLOT     64

typedef __attribute__((ext_vector_type(8))) short bf16x8;
typedef __attribute__((ext_vector_type(4))) float f32x4;

__device__ __forceinline__ float rcpf(float x) { return __builtin_amdgcn_rcpf(x); }

__device__ __forceinline__ short f2bf(float f) {
    union { float f; unsigned u; } v; v.f = f;
    unsigned r = (v.u + 0x7fffu + ((v.u >> 16) & 1u)) >> 16;
    return (short)r;
}

__device__ __forceinline__ void cvt8r(float4 a, float4 b, bf16x8& o, float& sq) {
    sq = fmaf(a.x, a.x, sq); sq = fmaf(a.y, a.y, sq);
    sq = fmaf(a.z, a.z, sq); sq = fmaf(a.w, a.w, sq);
    sq = fmaf(b.x, b.x, sq); sq = fmaf(b.y, b.y, sq);
    sq = fmaf(b.z, b.z, sq); sq = fmaf(b.w, b.w, sq);
    o[0] = f2bf(a.x); o[1] = f2bf(a.y); o[2] = f2bf(a.z); o[3] = f2bf(a.w);
    o[4] = f2bf(b.x); o[5] = f2bf(b.y); o[6] = f2bf(b.z); o[7] = f2bf(b.w);
}

__device__ __forceinline__ void cvt8(const float* __restrict__ p, bf16x8& o, float& sq) {
    float4 a = *(const float4*)p;
    float4 b = *(const float4*)(p + 4);
    cvt8r(a, b, o, sq);
}

// ---- lane ids ----
#define LANE_IDS()                                                             \
    const int tid = threadIdx.x;                                               \
    const int l   = tid & 63;                                                  \
    const int w   = tid >> 6;                                                  \
    const int c16 = l & 15;                                                    \
    const int g   = l >> 4;

// ---- B fragments + ||c||^2 in-register ----
#define PROLOGUE_B()                                                           \
    bf16x8 bfrag[NT][2];                                                       \
    float  cn2v[NT];                                                           \
    _Pragma("unroll")                                                          \
    for (int t = 0; t < NT; ++t) {                                             \
        int col = t * 16 + c16;                                                \
        bool valid = col < K_CL;                                               \
        float sq = 0.f;                                                        \
        _Pragma("unroll")                                                      \
        for (int kt = 0; kt < 2; ++kt) {                                       \
            bf16x8 bf;                                                         \
            if (valid) {                                                       \
                cvt8(cen + col * D_LAT + kt * 32 + g * 8, bf, sq);             \
            } else {                                                           \
                _Pragma("unroll")                                              \
                for (int i = 0; i < 8; ++i) bf[i] = 0;                         \
            }                                                                  \
            bfrag[t][kt] = bf;                                                 \
        }                                                                      \
        sq += __shfl_xor(sq, 16);                                              \
        sq += __shfl_xor(sq, 32);                                              \
        cn2v[t] = sq;                                                          \
    }                                                                          \
    const bool v6 = (c16 < 4); /* tile 6: cols 96..111, valid < 100 */

// ---- issue one group's enc loads into a named float4[4] ----
#define LOADS4(grp, A)                                                         \
    {                                                                          \
        const int rowbase_ = (grp) * 64 + w * 16;                              \
        const float* arow_ = enc + (size_t)(rowbase_ + c16) * D_LAT + g * 8;   \
        A[0] = *(const float4*)(arow_);                                        \
        A[1] = *(const float4*)(arow_ + 4);                                    \
        A[2] = *(const float4*)(arow_ + 32);                                   \
        A[3] = *(const float4*)(arow_ + 36);                                   \
    }

// ---- convert, MFMA dot, q + row-sums -> qv[NT][4], rs[4] (reads A[0..3]) ----
#define GROUP_COMPUTE_FROM(A)                                                  \
    float en2p = 0.f;                                                          \
    bf16x8 afrag0, afrag1;                                                     \
    cvt8r(A[0], A[1], afrag0, en2p);                                           \
    cvt8r(A[2], A[3], afrag1, en2p);                                           \
    en2p += __shfl_xor(en2p, 16);                                              \
    en2p += __shfl_xor(en2p, 32);                                              \
    f32x4 acc[NT];                                                             \
    _Pragma("unroll")                                                          \
    for (int t = 0; t < NT; ++t) {                                             \
        acc[t][0] = 0.f; acc[t][1] = 0.f; acc[t][2] = 0.f; acc[t][3] = 0.f;    \
    }                                                                          \
    _Pragma("unroll")                                                          \
    for (int t = 0; t < NT; ++t)                                               \
        acc[t] = __builtin_amdgcn_mfma_f32_16x16x32_bf16(afrag0, bfrag[t][0], acc[t], 0, 0, 0); \
    _Pragma("unroll")                                                          \
    for (int t = 0; t < NT; ++t)                                               \
        acc[t] = __builtin_amdgcn_mfma_f32_16x16x32_bf16(afrag1, bfrag[t][1], acc[t], 0, 0, 0); \
    float en2r[4];                                                             \
    _Pragma("unroll")                                                          \
    for (int r = 0; r < 4; ++r) en2r[r] = __shfl(en2p, g * 4 + r);             \
    float qv[NT][4];                                                           \
    float rs[4] = {0.f, 0.f, 0.f, 0.f};                                        \
    _Pragma("unroll")                                                          \
    for (int t = 0; t < NT; ++t) {                                             \
        _Pragma("unroll")                                                      \
        for (int r = 0; r < 4; ++r) {                                          \
            float d2 = en2r[r] + cn2v[t] - 2.f * acc[t][r];                    \
            float q = rcpf(1.f + fmaxf(d2, 0.f));                              \
            if (t == 6 && !v6) q = 0.f;                                        \
            qv[t][r] = q; rs[r] += q;                                          \
        }                                                                      \
    }                                                                          \
    _Pragma("unroll")                                                          \
    for (int r = 0; r < 4; ++r) {                                              \
        rs[r] += __shfl_xor(rs[r], 1); rs[r] += __shfl_xor(rs[r], 2);          \
        rs[r] += __shfl_xor(rs[r], 4); rs[r] += __shfl_xor(rs[r], 8);          \
        rs[r] = rcpf(rs[r]);                                                   \
    }

// ---- decoder-loss stream: persistent blocks, 16 loads in flight ----
__device__ __forceinline__ void dec_stream(const f32x4* __restrict__ X,
                                           const f32x4* __restrict__ Dec,
                                           double* __restrict__ slots,
                                           int sid, int cbase) {
    float local = 0.f;
#pragma unroll 1
    for (int c = sid; c < SC_HALF; c += NSTR) {
        const int idx = (cbase + c) * 2048 + (int)threadIdx.x;
        f32x4 a[8], b[8];
#pragma unroll
        for (int u = 0; u < 8; ++u)
            a[u] = __builtin_nontemporal_load(X + idx + u * 256);
#pragma unroll
        for (int u = 0; u < 8; ++u)
            b[u] = __builtin_nontemporal_load(Dec + idx + u * 256);
        __builtin_amdgcn_sched_barrier(0);   // pin: all 16 loads issued before use
#pragma unroll
        for (int u = 0; u < 8; ++u) {
            f32x4 d = a[u] - b[u];
            local = fmaf(d.x, d.x, local); local = fmaf(d.y, d.y, local);
            local = fmaf(d.z, d.z, local); local = fmaf(d.w, d.w, local);
        }
    }
    __shared__ float red[TPB];
    red[threadIdx.x] = local;
    __syncthreads();
    for (int off = TPB / 2; off > 0; off >>= 1) {
        if (threadIdx.x < off) red[threadIdx.x] += red[threadIdx.x + off];
        __syncthreads();
    }
    if (threadIdx.x == 0) atomicAdd(&slots[sid & (NSLOT - 1)], (double)red[0]);
}

// ---- dispatch 1: pass1 blocks [0,625) + persistent stream blocks [625, 625+NSTR) ----
__global__ void __launch_bounds__(TPB) k_d1(const f32x4* __restrict__ X,
                                            const f32x4* __restrict__ Xdec,
                                            const float* __restrict__ enc,
                                            const float* __restrict__ cen,
                                            double* __restrict__ dec_slots,
                                            float* __restrict__ fg) {
    if (blockIdx.x >= NMF) {
        dec_stream(X, Xdec, dec_slots, (int)blockIdx.x - NMF, 0);
        return;
    }
    LANE_IDS();
    const int p1id = blockIdx.x;
    float4 abuf[2][4];
    LOADS4(p1id, abuf[0]);
    PROLOGUE_B();
    float facc[NT];
#pragma unroll
    for (int t = 0; t < NT; ++t) facc[t] = 0.f;
#pragma unroll
    for (int j = 0; j < GPB; ++j) {
        if (j + 1 < GPB) LOADS4(p1id + (j + 1) * NMF, abuf[(j + 1) & 1]);
        GROUP_COMPUTE_FROM(abuf[j & 1]);
#pragma unroll
        for (int t = 0; t < NT; ++t) {
            float a = 0.f;
#pragma unroll
            for (int r = 0; r < 4; ++r) a = fmaf(qv[t][r], rs[r], a);
            facc[t] += a;
        }
    }
    __shared__ float f_s[K_CL];
    for (int i = tid; i < K_CL; i += TPB) f_s[i] = 0.f;
    __syncthreads();
#pragma unroll
    for (int t = 0; t < NT; ++t) {
        float a = facc[t];
        a += __shfl_xor(a, 16);
        a += __shfl_xor(a, 32);
        int col = t * 16 + c16;
        if (g == 0 && col < K_CL) atomicAdd(&f_s[col], a);
    }
    __syncthreads();
    for (int i = tid; i < K_CL; i += TPB) atomicAdd(&fg[i], f_s[i]);
}

// ---- dispatch 2: pass2 blocks [0,625) + persistent stream blocks [625, 625+NSTR) ----
__global__ void __launch_bounds__(TPB) k_d2(const f32x4* __restrict__ X,
                                            const f32x4* __restrict__ Xdec,
                                            const float* __restrict__ enc,
                                            const float* __restrict__ cen,
                                            const float* __restrict__ fg,
                                            double* __restrict__ dec_slots,
                                            double* __restrict__ kl_slots) {
    if (blockIdx.x >= NMF) {
        dec_stream(X, Xdec, dec_slots, (int)blockIdx.x - NMF, SC_HALF);
        return;
    }
    LANE_IDS();
    const int p2id = blockIdx.x;
    float4 abuf[2][4];
    LOADS4(p2id, abuf[0]);
    PROLOGUE_B();
    float lfv[NT], rfv[NT];
#pragma unroll
    for (int t = 0; t < NT; ++t) {
        int col = t * 16 + c16;
        if (col < K_CL) {
            float fv = fg[col];
            lfv[t] = __logf(fv);
            rfv[t] = rcpf(fv);
        } else { lfv[t] = 0.f; rfv[t] = 0.f; }
    }
    float kl_local = 0.f;
#pragma unroll
    for (int j = 0; j < GPB; ++j) {
        if (j + 1 < GPB) LOADS4(p2id + (j + 1) * NMF, abuf[(j + 1) & 1]);
        GROUP_COMPUTE_FROM(abuf[j & 1]);
        float tac[4] = {0.f, 0.f, 0.f, 0.f};
        float Ap[4]  = {0.f, 0.f, 0.f, 0.f};
        float Bp[4]  = {0.f, 0.f, 0.f, 0.f};
#pragma unroll
        for (int t = 0; t < NT; ++t) {
#pragma unroll
            for (int r = 0; r < 4; ++r) {
                if (t == 6 && !v6) continue;      // masked col: q==0, avoid log(0)
                float q = qv[t][r] * rs[r];
                float pu = q * q * rfv[t];
                tac[r] += pu;
                Ap[r] = fmaf(pu, __logf(q), Ap[r]);
                Bp[r] = fmaf(pu, lfv[t], Bp[r]);
            }
        }
#pragma unroll
        for (int r = 0; r < 4; ++r) {
            tac[r] += __shfl_xor(tac[r], 1); tac[r] += __shfl_xor(tac[r], 2);
            tac[r] += __shfl_xor(tac[r], 4); tac[r] += __shfl_xor(tac[r], 8);
            Ap[r]  += __shfl_xor(Ap[r], 1);  Ap[r]  += __shfl_xor(Ap[r], 2);
            Ap[r]  += __shfl_xor(Ap[r], 4);  Ap[r]  += __shfl_xor(Ap[r], 8);
            Bp[r]  += __shfl_xor(Bp[r], 1);  Bp[r]  += __shfl_xor(Bp[r], 2);
            Bp[r]  += __shfl_xor(Bp[r], 4);  Bp[r]  += __shfl_xor(Bp[r], 8);
        }
        if (c16 == 0) {
#pragma unroll
            for (int r = 0; r < 4; ++r)
                kl_local += (Ap[r] - Bp[r]) * rcpf(tac[r]) - __logf(tac[r]);
        }
    }
    __shared__ float red[TPB];
    red[tid] = kl_local;
    __syncthreads();
    for (int off = TPB / 2; off > 0; off >>= 1) {
        if (tid < off) red[tid] += red[tid + off];
        __syncthreads();
    }
    if (tid == 0) atomicAdd(&kl_slots[p2id & (NSLOT - 1)], (double)red[0]);
}

__global__ void k_final(const double* __restrict__ dec_s,
                        const double* __restrict__ kl_s,
                        float* __restrict__ out) {
    int l = threadIdx.x;     // 64 threads = one wave
    double d = dec_s[l];
    double k = kl_s[l];
#pragma unroll
    for (int off = 32; off > 0; off >>= 1) {
        d += __shfl_xor(d, off);
        k += __shfl_xor(k, off);
    }
    if (l == 0)
        out[0] = (float)(d / ((double)N_ROWS * (double)D_IN) + 1000.0 * (k / (double)N_ROWS));
}

extern "C" void kernel_launch(void* const* d_in, const int* in_sizes, int n_in,
                              void* d_out, int out_size, void* d_ws, size_t ws_size,
                              hipStream_t stream) {
    (void)in_sizes; (void)n_in; (void)out_size; (void)ws_size;
    const float* X   = (const float*)d_in[0];
    const float* enc = (const float*)d_in[1];
    const float* dec = (const float*)d_in[2];
    const float* cen = (const float*)d_in[3];
    float* out = (float*)d_out;

    double* dec_slots = (double*)d_ws;                       // 64 doubles
    double* kl_slots  = (double*)((char*)d_ws + 512);        // 64 doubles
    float*  fg        = (float*)((char*)d_ws + 1024);        // 128 floats

    hipMemsetAsync(d_ws, 0, 1536, stream);
    k_d1<<<NMF + NSTR, TPB, 0, stream>>>(
        (const f32x4*)X, (const f32x4*)dec, enc, cen, dec_slots, fg);
    k_d2<<<NMF + NSTR, TPB, 0, stream>>>(
        (const f32x4*)X, (const f32x4*)dec, enc, cen, fg, dec_slots, kl_slots);
    k_final<<<1, 64, 0, stream>>>(dec_slots, kl_slots, out);
}